// Round 6
// baseline (2824.416 us; speedup 1.0000x reference)
//
#include <hip/hip_runtime.h>

// CRF forward chain on MI355X — linearized: u' = (1/g) diag(exp(h_s)) E u.
// R12: 4-chain 3-stage pipeline (poll -> pack -> GEMV) + drain-free barriers.
// R11 failed to hide sync: polling wave ran GEMV THEN poll (serialized), and
// every __syncthreads drained vmcnt(0) (store-acks on every barrier).
// Fixes: (1) poll split issue-early/finish-late, distributed over all 8 waves
// (1 dwordx4/lane); (2) rotation over 4 chains/group so polled data is 2
// phases old at the wait (visibility pre-paid); (3) raw s_barrier with
// lgkmcnt(0) only — stores stay in flight, ack'd by next phase's vmcnt(0).
// Geometry: 16 groups x 16 blocks (=256 = 1 blk/CU, proven regime), each
// group owns chains {g,16+g,32+g,48+g}. NCH=64, CH_LEN=128, BURN=24.
// Phases = 2 + 152*4 = 610, each: GEMV(16 rows/wave: 12 reg + 4 LDS rows)
// + pack(other chain) + poll(third chain) + ONE barrier.
// gmax determinism: all blocks compute slice-maxes over identical slices with
// identical reduction order -> bitwise-identical normalization across blocks.
//
// ws floats: u_bufs[64][2][2048] @0, usave[64][2048] @262144,
// ufin[64][2048] @393216, cbuf[64] @524288 ; posts int[2048] @byte 2097408.

#define TSZ   2048
#define NCH   64
#define GBLK  16
#define NW    8
#define CH_LEN 128
#define BURN  24
#define TCYC  (CH_LEN + BURN)
#define START_I 0
#define END_I   1

typedef float v4f __attribute__((ext_vector_type(4)));
typedef _Float16 h2f __attribute__((ext_vector_type(2)));

__device__ __forceinline__ h2f pk16(float a, float b) {
    return __builtin_bit_cast(h2f, __builtin_amdgcn_cvt_pkrtz(a, b));
}
__device__ __forceinline__ void st_coh(float* p, float v) {
    asm volatile("global_store_dword %0, %1, off sc0 sc1"
                 :: "v"(p), "v"(v) : "memory");
}
__device__ __forceinline__ float ld_coh1(const float* p) {
    float r;
    asm volatile("global_load_dword %0, %1, off sc0 sc1\n\ts_waitcnt vmcnt(0)"
                 : "=&v"(r) : "v"(p) : "memory");
    return r;
}
__device__ __forceinline__ v4f ld_coh4(const float* p) {
    v4f r;
    asm volatile("global_load_dwordx4 %0, %1, off sc0 sc1\n\ts_waitcnt vmcnt(0)"
                 : "=&v"(r) : "v"(p) : "memory");
    return r;
}

__global__ __launch_bounds__(512, 1)
void crf_chain(const float* __restrict__ h, const float* __restrict__ tr,
               float* __restrict__ out, float* __restrict__ ws)
{
    const int tid  = threadIdx.x;
    const int lane = tid & 63;
    const int wv   = tid >> 6;          // 0..7
    const int blk  = blockIdx.x;
    const int g    = blk >> 4;          // group 0..15
    const int b    = blk & (GBLK - 1);  // block within group 0..15
    const int row_base = b * 128 + wv * 16;

    float* u_bufs = ws;                               // [64][2][2048]
    float* usave  = ws + NCH * 2 * TSZ;               // [64][2048]
    float* ufin   = usave + NCH * TSZ;                // [64][2048]
    float* cbuf   = ufin + NCH * TSZ;                 // [64]
    int*   posts  = (int*)((char*)ws + 2097408);      // [2048]

    __shared__ unsigned long long els64[32][512];     // 4 LDS E-rows/wave, 128KB
    __shared__ unsigned long long uh_sh[4][512];      // packed u per chain, 16KB
    __shared__ float smax_sh[4][8] __attribute__((aligned(16)));

    // ---- one-time: register E fragment, 12 rows/wave.
    h2f e2r[12][16];
    #pragma unroll
    for (int r = 0; r < 12; ++r) {
        const float* trow = tr + (size_t)(row_base + r) * TSZ + 4 * lane;
        #pragma unroll
        for (int k = 0; k < 8; ++k) {
            float4 t4 = *(const float4*)(trow + 256 * k);
            e2r[r][2 * k]     = pk16(__expf(t4.x), __expf(t4.y));
            e2r[r][2 * k + 1] = pk16(__expf(t4.z), __expf(t4.w));
        }
    }
    // ---- one-time: LDS E rows 12..15 per wave.
    #pragma unroll
    for (int rr = 0; rr < 4; ++rr) {
        const float* trow = tr + (size_t)(row_base + 12 + rr) * TSZ + 4 * lane;
        #pragma unroll
        for (int k = 0; k < 8; ++k) {
            float4 t4 = *(const float4*)(trow + 256 * k);
            unsigned lo = __builtin_bit_cast(unsigned, pk16(__expf(t4.x), __expf(t4.y)));
            unsigned hi = __builtin_bit_cast(unsigned, pk16(__expf(t4.z), __expf(t4.w)));
            els64[wv * 4 + rr][lane + 64 * k] =
                ((unsigned long long)hi << 32) | (unsigned long long)lo;
        }
    }

    // per-chain constants (constant-indexed under unrolled phases)
    const int ccs[4] = { g, 16 + g, 32 + g, 48 + g };
    int s0s[4], sks[4], ses[4];
    float* ubs[4];
    #pragma unroll
    for (int r = 0; r < 4; ++r) {
        sks[r] = ccs[r] * CH_LEN;
        ses[r] = sks[r] + CH_LEN;
        s0s[r] = (ccs[r] == 0) ? 0 : (sks[r] - BURN);
        ubs[r] = u_bufs + ccs[r] * 2 * TSZ;
    }

    const int q    = ((lane & 1) << 2) | (lane & 2) | ((lane >> 2) & 1);
    const int grow = row_base + q;          // rows grow, grow+8 for lane<8

    // ---- init: u^0 parity 0, POSITIVE tag (ws poison 0xAA.. is negative)
    if (tid < 128) {
        int row = b * 128 + tid;
        #pragma unroll
        for (int r = 0; r < 4; ++r)
            st_coh(&ubs[r][row],
                   (ccs[r] == 0) ? ((row == START_I) ? 1.0f : 0.0f) : 1.0f);
    }
    __syncthreads();   // els64 ready

    float Chat[4] = {0.0f, 0.0f, 0.0f, 0.0f};
    v4f pu = {};       // polled slice carried between phases (chain rotates)

    // ---- distributed poll: wave wv owns u[wv*256 + 4*lane .. +3]
    auto POLL_ISSUE = [&](const float* ubase, int par) -> v4f {
        v4f r;
        const float* p = ubase + par * TSZ + (wv << 8) + 4 * lane;
        asm volatile("global_load_dwordx4 %0, %1, off sc0 sc1"
                     : "=&v"(r) : "v"(p) : "memory");
        return r;
    };
    auto POLL_FINISH = [&](v4f& pv, const float* ubase, int par, int in_neg, int cidx) {
        const float* p = ubase + par * TSZ + (wv << 8) + 4 * lane;
        asm volatile("s_waitcnt vmcnt(0)" : "+v"(pv) :: "memory");
        for (;;) {
            int a0 = __float_as_int(pv.x), a1 = __float_as_int(pv.y);
            int a2 = __float_as_int(pv.z), a3 = __float_as_int(pv.w);
            bool fresh = in_neg ? (((a0 & a1) & (a2 & a3)) < 0)
                                : (((a0 | a1) | (a2 | a3)) >= 0);
            if (__all(fresh)) break;
            asm volatile("global_load_dwordx4 %0, %1, off sc0 sc1\n\ts_waitcnt vmcnt(0)"
                         : "=&v"(pv) : "v"(p) : "memory");
        }
        float m = fmaxf(fmaxf(fabsf(pv.x), fabsf(pv.y)),
                        fmaxf(fabsf(pv.z), fabsf(pv.w)));
        #pragma unroll
        for (int d = 1; d < 64; d <<= 1) m = fmaxf(m, __shfl_xor(m, d, 64));
        if (lane == 0) smax_sh[cidx][wv] = m;
    };
    // pack: gmax from 8 slice-maxes (fixed order => identical in all blocks),
    // normalize own 4 values, write packed pair to uh_sh slot (lane + 64*wv).
    auto PACK = [&](v4f pv, int in_neg, bool kept, float& ch, int cidx) {
        v4f m0 = *(const v4f*)&smax_sh[cidx][0];
        v4f m1 = *(const v4f*)&smax_sh[cidx][4];
        float gm = fmaxf(fmaxf(fmaxf(m0.x, m0.y), fmaxf(m0.z, m0.w)),
                         fmaxf(fmaxf(m1.x, m1.y), fmaxf(m1.z, m1.w)));
        float rn = (in_neg ? -1.0f : 1.0f) / gm;
        unsigned lo = __builtin_bit_cast(unsigned, pk16(pv.x * rn, pv.y * rn));
        unsigned hi = __builtin_bit_cast(unsigned, pk16(pv.z * rn, pv.w * rn));
        uh_sh[cidx][lane + 64 * wv] =
            ((unsigned long long)hi << 32) | (unsigned long long)lo;
        if (kept) ch += __logf(gm);
    };

    // ---- GEMV (16 rows/wave: 12 reg + 4 LDS), no stores
    auto GEMV_COMPUTE = [&](const unsigned long long* uh_src, float& outA, float& outB) {
        h2f uh[16];
        #pragma unroll
        for (int k = 0; k < 8; ++k) {
            unsigned long long qw = uh_src[lane + 64 * k];
            uh[2 * k]     = __builtin_bit_cast(h2f, (unsigned)qw);
            uh[2 * k + 1] = __builtin_bit_cast(h2f, (unsigned)(qw >> 32));
        }
        float acc[8];
        #pragma unroll
        for (int r = 0; r < 8; ++r) acc[r] = 0.0f;
        #pragma unroll
        for (int k = 0; k < 16; ++k) {
            #pragma unroll
            for (int r = 0; r < 8; ++r)
                acc[r] = __builtin_amdgcn_fdot2(e2r[r][k], uh[k], acc[r], false);
        }
        #pragma unroll
        for (int r = 0; r < 4; ++r) {
            float send = (lane & 1) ? acc[r] : acc[r + 4];
            float recv = __shfl_xor(send, 1, 64);
            float keep = (lane & 1) ? acc[r + 4] : acc[r];
            acc[r] = keep + recv;
        }
        #pragma unroll
        for (int r = 0; r < 2; ++r) {
            float send = (lane & 2) ? acc[r] : acc[r + 2];
            float recv = __shfl_xor(send, 2, 64);
            float keep = (lane & 2) ? acc[r + 2] : acc[r];
            acc[r] = keep + recv;
        }
        {
            float send = (lane & 4) ? acc[0] : acc[1];
            float recv = __shfl_xor(send, 4, 64);
            float keep = (lane & 4) ? acc[1] : acc[0];
            acc[0] = keep + recv;
        }
        acc[0] += __shfl_xor(acc[0], 8, 64);
        acc[0] += __shfl_xor(acc[0], 16, 64);
        acc[0] += __shfl_xor(acc[0], 32, 64);
        outA = acc[0];

        #pragma unroll
        for (int r = 0; r < 8; ++r) acc[r] = 0.0f;
        #pragma unroll
        for (int k = 0; k < 8; ++k) {
            unsigned long long q0 = els64[wv * 4 + 0][lane + 64 * k];
            unsigned long long q1 = els64[wv * 4 + 1][lane + 64 * k];
            unsigned long long q2 = els64[wv * 4 + 2][lane + 64 * k];
            unsigned long long q3 = els64[wv * 4 + 3][lane + 64 * k];
            #pragma unroll
            for (int r = 0; r < 4; ++r) {
                acc[r] = __builtin_amdgcn_fdot2(e2r[8 + r][2 * k],     uh[2 * k],     acc[r], false);
                acc[r] = __builtin_amdgcn_fdot2(e2r[8 + r][2 * k + 1], uh[2 * k + 1], acc[r], false);
            }
            acc[4] = __builtin_amdgcn_fdot2(__builtin_bit_cast(h2f, (unsigned)q0),         uh[2 * k],     acc[4], false);
            acc[4] = __builtin_amdgcn_fdot2(__builtin_bit_cast(h2f, (unsigned)(q0 >> 32)), uh[2 * k + 1], acc[4], false);
            acc[5] = __builtin_amdgcn_fdot2(__builtin_bit_cast(h2f, (unsigned)q1),         uh[2 * k],     acc[5], false);
            acc[5] = __builtin_amdgcn_fdot2(__builtin_bit_cast(h2f, (unsigned)(q1 >> 32)), uh[2 * k + 1], acc[5], false);
            acc[6] = __builtin_amdgcn_fdot2(__builtin_bit_cast(h2f, (unsigned)q2),         uh[2 * k],     acc[6], false);
            acc[6] = __builtin_amdgcn_fdot2(__builtin_bit_cast(h2f, (unsigned)(q2 >> 32)), uh[2 * k + 1], acc[6], false);
            acc[7] = __builtin_amdgcn_fdot2(__builtin_bit_cast(h2f, (unsigned)q3),         uh[2 * k],     acc[7], false);
            acc[7] = __builtin_amdgcn_fdot2(__builtin_bit_cast(h2f, (unsigned)(q3 >> 32)), uh[2 * k + 1], acc[7], false);
        }
        #pragma unroll
        for (int r = 0; r < 4; ++r) {
            float send = (lane & 1) ? acc[r] : acc[r + 4];
            float recv = __shfl_xor(send, 1, 64);
            float keep = (lane & 1) ? acc[r + 4] : acc[r];
            acc[r] = keep + recv;
        }
        #pragma unroll
        for (int r = 0; r < 2; ++r) {
            float send = (lane & 2) ? acc[r] : acc[r + 2];
            float recv = __shfl_xor(send, 2, 64);
            float keep = (lane & 2) ? acc[r + 2] : acc[r];
            acc[r] = keep + recv;
        }
        {
            float send = (lane & 4) ? acc[0] : acc[1];
            float recv = __shfl_xor(send, 4, 64);
            float keep = (lane & 4) ? acc[1] : acc[0];
            acc[0] = keep + recv;
        }
        acc[0] += __shfl_xor(acc[0], 8, 64);
        acc[0] += __shfl_xor(acc[0], 16, 64);
        acc[0] += __shfl_xor(acc[0], 32, 64);
        outB = acc[0];
    };

    // drain-free barrier: LDS consistency only; stores stay in flight.
    auto BAR = [&]() {
        __builtin_amdgcn_sched_barrier(0);
        asm volatile("s_waitcnt lgkmcnt(0)" ::: "memory");
        __builtin_amdgcn_s_barrier();
        __builtin_amdgcn_sched_barrier(0);
    };

    // ---- pipeline prologue
    {   // P-2: poll chain 0 u(0)
        v4f p0 = POLL_ISSUE(ubs[0], 0);
        POLL_FINISH(p0, ubs[0], 0, 0, 0);
        pu = p0;
        BAR();
    }
    {   // P-1: pack chain 0 (t=0); poll chain 1 u(0)
        v4f p1 = POLL_ISSUE(ubs[1], 0);
        const int spk = s0s[0];
        PACK(pu, 0, (spk + 1 > sks[0]) && (spk + 1 <= ses[0]), Chat[0], 0);
        POLL_FINISH(p1, ubs[1], 0, 0, 1);
        pu = p1;
        BAR();
    }

#define PHASE(T_, R_) do {                                                    \
    constexpr int A_ = (R_) & 3;                                              \
    constexpr int B_ = ((R_) + 1) & 3;                                        \
    constexpr int C_ = ((R_) + 2) & 3;                                        \
    const int tB_ = (B_ <= (R_)) ? (T_) + 1 : (T_);                           \
    const int tC_ = (C_ <= (R_)) ? (T_) + 1 : (T_);                           \
    const int sA_ = s0s[A_] + (T_);                                           \
    float hA0_ = 0.0f, hA1_ = 0.0f;                                           \
    if (lane < 8) {                                                           \
        hA0_ = h[(size_t)sA_ * TSZ + grow];                                   \
        hA1_ = h[(size_t)sA_ * TSZ + grow + 8];                               \
    }                                                                         \
    const bool doPoll_ = (tC_ < TCYC);                                        \
    const bool doPack_ = (tB_ < TCYC);                                        \
    v4f pnew_ = {};                                                           \
    if (doPoll_) pnew_ = POLL_ISSUE(ubs[C_], tC_ & 1);                        \
    if (doPack_) {                                                            \
        const int spk_ = s0s[B_] + tB_;                                       \
        PACK(pu, (tB_ >> 1) & 1,                                              \
             (spk_ + 1 > sks[B_]) && (spk_ + 1 <= ses[B_]), Chat[B_], B_);    \
    }                                                                         \
    float resA_, resB_;                                                       \
    GEMV_COMPUTE(&uh_sh[A_][0], resA_, resB_);                                \
    if (doPoll_) POLL_FINISH(pnew_, ubs[C_], tC_ & 1, (tC_ >> 1) & 1, C_);    \
    {                                                                         \
        const int outp_ = ((T_) + 1) & 1, outn_ = (((T_) + 1) >> 1) & 1;      \
        if (lane < 8) {                                                       \
            float utA_ = resA_ * __expf(hA0_);                                \
            float utB_ = resB_ * __expf(hA1_);                                \
            float* uo_ = ubs[A_] + outp_ * TSZ;                               \
            st_coh(&uo_[grow],     outn_ ? -utA_ : utA_);                     \
            st_coh(&uo_[grow + 8], outn_ ? -utB_ : utB_);                     \
            if (ccs[A_] > 0 && sA_ + 1 == sks[A_]) {                          \
                st_coh(&usave[ccs[A_] * TSZ + grow],     utA_);               \
                st_coh(&usave[ccs[A_] * TSZ + grow + 8], utB_);               \
            }                                                                 \
            if (sA_ + 1 == ses[A_]) {                                         \
                st_coh(&ufin[ccs[A_] * TSZ + grow],     utA_);                \
                st_coh(&ufin[ccs[A_] * TSZ + grow + 8], utB_);                \
            }                                                                 \
        }                                                                     \
    }                                                                         \
    if (doPoll_) pu = pnew_;                                                  \
    BAR();                                                                    \
} while (0)

    for (int T = 0; T < TCYC; ++T) {
        PHASE(T, 0);
        PHASE(T, 1);
        PHASE(T, 2);
        PHASE(T, 3);
    }
#undef PHASE

    // ---- completion: store Chats, ack all stores, per-wave post
    if (b == 0 && wv == 0 && lane == 0) {
        #pragma unroll
        for (int r = 0; r < 4; ++r) st_coh(&cbuf[ccs[r]], Chat[r]);
    }
    asm volatile("s_waitcnt vmcnt(0)" ::: "memory");
    if (lane == 0)
        __hip_atomic_store(&posts[blk * NW + wv], 1,
                           __ATOMIC_RELAXED, __HIP_MEMORY_SCOPE_AGENT);

    // ---- finisher: block 0 / wave 0 stitches 64 chunks
    if (blk == 0 && wv == 0) {
        int ok;
        do {
            __builtin_amdgcn_s_sleep(1);
            ok = 1;
            #pragma unroll
            for (int i = 0; i < 32; ++i) {     // 256 blocks x 8 waves = 2048
                int v = __hip_atomic_load(&posts[lane + 64 * i],
                                          __ATOMIC_RELAXED, __HIP_MEMORY_SCOPE_AGENT);
                ok &= (v == 1);
            }
        } while (!__all(ok));

        float O = 0.0f;
        for (int cc = 1; cc < NCH; ++cc) {
            float sa = 0.0f, sb = 0.0f;
            for (int j = 4 * lane; j < TSZ; j += 256) {
                v4f a4 = ld_coh4(&ufin[(cc - 1) * TSZ + j]);
                v4f b4 = ld_coh4(&usave[cc * TSZ + j]);
                sa += a4.x + a4.y + a4.z + a4.w;
                sb += b4.x + b4.y + b4.z + b4.w;
            }
            #pragma unroll
            for (int d = 1; d < 64; d <<= 1) {
                sa += __shfl_xor(sa, d, 64);
                sb += __shfl_xor(sb, d, 64);
            }
            O += ld_coh1(&cbuf[cc - 1]) + __logf(sa) - __logf(sb);
        }
        float se = 0.0f;
        for (int j = 4 * lane; j < TSZ; j += 256) {
            const float4 t4 = *(const float4*)(tr + (size_t)END_I * TSZ + j);
            v4f uf = ld_coh4(&ufin[(NCH - 1) * TSZ + j]);
            se += __expf(t4.x) * uf.x + __expf(t4.y) * uf.y +
                  __expf(t4.z) * uf.z + __expf(t4.w) * uf.w;
        }
        #pragma unroll
        for (int d = 1; d < 64; d <<= 1) se += __shfl_xor(se, d, 64);

        float ans = O + ld_coh1(&cbuf[NCH - 1]) + __logf(se);
        if (lane == 0) out[0] = ans;
    }
}

extern "C" void kernel_launch(void* const* d_in, const int* in_sizes, int n_in,
                              void* d_out, int out_size, void* d_ws, size_t ws_size,
                              hipStream_t stream) {
    const float* h  = (const float*)d_in[0];   // [8192, 2048] fp32 emissions
    const float* tr = (const float*)d_in[1];   // [2048, 2048] fp32 transitions
    (void)in_sizes; (void)n_in; (void)out_size; (void)ws_size;
    crf_chain<<<dim3(256), dim3(512), 0, stream>>>(h, tr, (float*)d_out, (float*)d_ws);
}